// Round 3
// baseline (6668.694 us; speedup 1.0000x reference)
//
#include <hip/hip_runtime.h>
#include <cstdint>

#define B_SZ 64
#define T_SZ 2048
#define F_SZ 256
#define H_SZ 512

typedef _Float16 f16x8 __attribute__((ext_vector_type(8)));
typedef _Float16 f16x4 __attribute__((ext_vector_type(4)));
typedef float f32x4 __attribute__((ext_vector_type(4)));

#if defined(__has_builtin)
#if __has_builtin(__builtin_amdgcn_fdot2)
#define HAVE_FDOT2 1
#endif
#endif
#ifndef HAVE_FDOT2
#define HAVE_FDOT2 0
#endif

typedef _Float16 half2v __attribute__((ext_vector_type(2)));
union H2U { uint32_t u; half2v h; _Float16 e[2]; };

__device__ __forceinline__ float fdot2f(uint32_t a, uint32_t b, float c) {
  H2U ua, ub; ua.u = a; ub.u = b;
#if HAVE_FDOT2
  return __builtin_amdgcn_fdot2(ua.h, ub.h, c, false);
#else
  return c + (float)ua.e[0] * (float)ub.e[0] + (float)ua.e[1] * (float)ub.e[1];
#endif
}

__device__ __forceinline__ uint32_t pack2h(float x, float y) {
  H2U v; v.e[0] = (_Float16)x; v.e[1] = (_Float16)y; return v.u;
}

__device__ __forceinline__ float fast_tanh(float x) {
  float xc = fminf(9.0f, fmaxf(-9.0f, x));
  float e = __expf(2.0f * xc);
  return (e - 1.0f) / (e + 1.0f);
}

// ---------------------------------------------------------------------------
// Kernel 1: xp[m,n] = q·W_ih^T + b_ih + b_hh   (unchanged — not bottleneck)
// ---------------------------------------------------------------------------
__global__ __launch_bounds__(256) void proj_kernel(
    const float* __restrict__ q, const float* __restrict__ w_ih,
    const float* __restrict__ b_ih, const float* __restrict__ b_hh,
    float* __restrict__ xp) {
  __shared__ uint32_t lds_a[16][128 + 4];
  __shared__ uint32_t lds_b[16][128 + 4];
  const int tid = threadIdx.x;
  const int nt = blockIdx.x & 3;
  const int mt = blockIdx.x >> 2;
  const int m0 = mt * 128, n0 = nt * 128;
  const int tx = tid & 15, ty = tid >> 4;
  const int sr = tid >> 3, sc4 = tid & 7;

  float bias[8];
#pragma unroll
  for (int j = 0; j < 8; ++j) {
    int n = n0 + tx * 8 + j;
    bias[j] = b_ih[n] + b_hh[n];
  }
  float acc[8][8];
#pragma unroll
  for (int i = 0; i < 8; ++i)
#pragma unroll
    for (int j = 0; j < 8; ++j) acc[i][j] = 0.f;

  for (int k0 = 0; k0 < F_SZ; k0 += 32) {
#pragma unroll
    for (int i = 0; i < 4; ++i) {
      int r = sr + 32 * i;
      float4 v = *(const float4*)(q + (size_t)(m0 + r) * F_SZ + k0 + sc4 * 4);
      lds_a[sc4 * 2 + 0][r] = pack2h(v.x, v.y);
      lds_a[sc4 * 2 + 1][r] = pack2h(v.z, v.w);
      float4 w = *(const float4*)(w_ih + (size_t)(n0 + r) * F_SZ + k0 + sc4 * 4);
      lds_b[sc4 * 2 + 0][r] = pack2h(w.x, w.y);
      lds_b[sc4 * 2 + 1][r] = pack2h(w.z, w.w);
    }
    __syncthreads();
#pragma unroll
    for (int kp = 0; kp < 16; ++kp) {
      uint32_t a8[8], b8[8];
#pragma unroll
      for (int i = 0; i < 8; ++i) a8[i] = lds_a[kp][ty * 8 + i];
#pragma unroll
      for (int j = 0; j < 8; ++j) b8[j] = lds_b[kp][tx * 8 + j];
#pragma unroll
      for (int i = 0; i < 8; ++i)
#pragma unroll
        for (int j = 0; j < 8; ++j)
          acc[i][j] = fdot2f(a8[i], b8[j], acc[i][j]);
    }
    __syncthreads();
  }
#pragma unroll
  for (int i = 0; i < 8; ++i) {
    size_t row = (size_t)(m0 + ty * 8 + i);
    float4 o0, o1;
    o0.x = acc[i][0] + bias[0]; o0.y = acc[i][1] + bias[1];
    o0.z = acc[i][2] + bias[2]; o0.w = acc[i][3] + bias[3];
    o1.x = acc[i][4] + bias[4]; o1.y = acc[i][5] + bias[5];
    o1.z = acc[i][6] + bias[6]; o1.w = acc[i][7] + bias[7];
    *(float4*)(xp + row * H_SZ + n0 + tx * 8) = o0;
    *(float4*)(xp + row * H_SZ + n0 + tx * 8 + 4) = o1;
  }
}

// ---------------------------------------------------------------------------
// Kernel 2: recurrence via MFMA. One 512-thread WG (8 waves) per batch row.
// W_hh fp16 as mfma_f32_16x16x32_f16 A-fragments:
//   wave w: rows 48w..48w+47 in registers (3 row-tiles x 16 k-tiles x 4 VGPR
//   = 192 regs; AGPR placement is fine — MFMA reads AGPRs natively),
//   rows 384+16w..+15 as LDS fragments (128 KB, lane-linear b128 reads).
// h: plain fp16[512], double-buffered; B-frag reads are 16-lane broadcasts
// (free). All 16 MFMA N-columns compute the same (correct) dot — no reduce.
// C/D layout (HW-verified): col=lane&15, row=(lane>>4)*4+reg.
// ---------------------------------------------------------------------------
__global__ __attribute__((amdgpu_flat_work_group_size(512, 512),
                          amdgpu_waves_per_eu(2, 2)))
void rnn_kernel(const float* __restrict__ w_hh, float* __restrict__ out) {
  extern __shared__ char smem[];
  uint4* lds_wf = (uint4*)smem;                    // 8w x 16kt x 64 lanes x 16B
  _Float16* lds_h = (_Float16*)(smem + 131072);    // 2 x 512

  const int b = blockIdx.x;
  const int tid = threadIdx.x;
  const int w = tid >> 6;
  const int lane = tid & 63;
  const int mrow = lane & 15;   // A row / C col
  const int g = lane >> 4;      // k-group / C row-group

  // --- register A-fragments: rows 48w + vr*16 + mrow, k = kt*32 + g*8 + i ---
  f16x8 af[3][16];
#pragma unroll
  for (int vr = 0; vr < 3; ++vr) {
    const float* rowp = w_hh + (size_t)(48 * w + vr * 16 + mrow) * H_SZ;
#pragma unroll
    for (int kt = 0; kt < 16; ++kt) {
      const float* p = rowp + kt * 32 + g * 8;
      float4 v0 = *(const float4*)p;
      float4 v1 = *(const float4*)(p + 4);
      f16x8 a;
      a[0] = (_Float16)v0.x; a[1] = (_Float16)v0.y;
      a[2] = (_Float16)v0.z; a[3] = (_Float16)v0.w;
      a[4] = (_Float16)v1.x; a[5] = (_Float16)v1.y;
      a[6] = (_Float16)v1.z; a[7] = (_Float16)v1.w;
      af[vr][kt] = a;
    }
  }
  // --- LDS A-fragments: rows 384 + 16w + mrow ---
  {
    const float* rowp = w_hh + (size_t)(384 + 16 * w + mrow) * H_SZ;
#pragma unroll
    for (int kt = 0; kt < 16; ++kt) {
      const float* p = rowp + kt * 32 + g * 8;
      float4 v0 = *(const float4*)p;
      float4 v1 = *(const float4*)(p + 4);
      f16x8 a;
      a[0] = (_Float16)v0.x; a[1] = (_Float16)v0.y;
      a[2] = (_Float16)v0.z; a[3] = (_Float16)v0.w;
      a[4] = (_Float16)v1.x; a[5] = (_Float16)v1.y;
      a[6] = (_Float16)v1.z; a[7] = (_Float16)v1.w;
      lds_wf[(w * 16 + kt) * 64 + lane] = __builtin_bit_cast(uint4, a);
    }
  }
  // h0 = 0, both buffers
  lds_h[tid] = (_Float16)0.f;
  lds_h[512 + tid] = (_Float16)0.f;
  __syncthreads();

  const int r0 = 48 * w + g * 4;          // C-frag 0 rows (on mrow==0 lanes)
  const int r3 = 384 + 16 * w + g * 4;    // LDS-tile C-frag rows
  float* outb = out + (size_t)b * T_SZ * H_SZ;
  const bool wlane = (mrow == 0);
  const uint4* wl = lds_wf + (w * 16) * 64 + lane;

  float4 xc0, xc1, xc2, xc3;
  if (wlane) {
    xc0 = *(const float4*)(outb + r0);
    xc1 = *(const float4*)(outb + r0 + 16);
    xc2 = *(const float4*)(outb + r0 + 32);
    xc3 = *(const float4*)(outb + r3);
  }

#pragma unroll 1
  for (int t = 0; t < T_SZ; ++t) {
    // prefetch next step's xp (HBM latency hides under the MFMA phase)
    float4 xn0, xn1, xn2, xn3;
    if (wlane) {
      int tn = (t + 1 < T_SZ) ? t + 1 : t;
      const float* pn = outb + (size_t)tn * H_SZ;
      xn0 = *(const float4*)(pn + r0);
      xn1 = *(const float4*)(pn + r0 + 16);
      xn2 = *(const float4*)(pn + r0 + 32);
      xn3 = *(const float4*)(pn + r3);
    }

    const _Float16* hb = lds_h + (t & 1) * 512;
    f32x4 c0 = {0.f, 0.f, 0.f, 0.f}, c1 = c0, c2 = c0, c3 = c0;
#pragma unroll
    for (int kt = 0; kt < 16; ++kt) {
      f16x8 bf = *(const f16x8*)(hb + kt * 32 + g * 8);  // broadcast read
      c0 = __builtin_amdgcn_mfma_f32_16x16x32_f16(af[0][kt], bf, c0, 0, 0, 0);
      c1 = __builtin_amdgcn_mfma_f32_16x16x32_f16(af[1][kt], bf, c1, 0, 0, 0);
      c2 = __builtin_amdgcn_mfma_f32_16x16x32_f16(af[2][kt], bf, c2, 0, 0, 0);
      uint4 aq = wl[kt * 64];
      c3 = __builtin_amdgcn_mfma_f32_16x16x32_f16(
          __builtin_bit_cast(f16x8, aq), bf, c3, 0, 0, 0);
    }

    if (wlane) {
      _Float16* hn = lds_h + ((t + 1) & 1) * 512;
      float* po = outb + (size_t)t * H_SZ;
      float4 o; f16x4 hh;

      o.x = fast_tanh(xc0.x + c0[0]); o.y = fast_tanh(xc0.y + c0[1]);
      o.z = fast_tanh(xc0.z + c0[2]); o.w = fast_tanh(xc0.w + c0[3]);
      *(float4*)(po + r0) = o;
      hh[0] = (_Float16)o.x; hh[1] = (_Float16)o.y;
      hh[2] = (_Float16)o.z; hh[3] = (_Float16)o.w;
      *(f16x4*)(hn + r0) = hh;

      o.x = fast_tanh(xc1.x + c1[0]); o.y = fast_tanh(xc1.y + c1[1]);
      o.z = fast_tanh(xc1.z + c1[2]); o.w = fast_tanh(xc1.w + c1[3]);
      *(float4*)(po + r0 + 16) = o;
      hh[0] = (_Float16)o.x; hh[1] = (_Float16)o.y;
      hh[2] = (_Float16)o.z; hh[3] = (_Float16)o.w;
      *(f16x4*)(hn + r0 + 16) = hh;

      o.x = fast_tanh(xc2.x + c2[0]); o.y = fast_tanh(xc2.y + c2[1]);
      o.z = fast_tanh(xc2.z + c2[2]); o.w = fast_tanh(xc2.w + c2[3]);
      *(float4*)(po + r0 + 32) = o;
      hh[0] = (_Float16)o.x; hh[1] = (_Float16)o.y;
      hh[2] = (_Float16)o.z; hh[3] = (_Float16)o.w;
      *(f16x4*)(hn + r0 + 32) = hh;

      o.x = fast_tanh(xc3.x + c3[0]); o.y = fast_tanh(xc3.y + c3[1]);
      o.z = fast_tanh(xc3.z + c3[2]); o.w = fast_tanh(xc3.w + c3[3]);
      *(float4*)(po + r3) = o;
      hh[0] = (_Float16)o.x; hh[1] = (_Float16)o.y;
      hh[2] = (_Float16)o.z; hh[3] = (_Float16)o.w;
      *(f16x4*)(hn + r3) = hh;

      xc0 = xn0; xc1 = xn1; xc2 = xn2; xc3 = xn3;
    }
    __syncthreads();
  }

  // hidden = h_{T-1}; T even -> final h lives in buffer 0
  out[(size_t)B_SZ * T_SZ * H_SZ + (size_t)b * H_SZ + tid] =
      (float)lds_h[(T_SZ & 1) * 512 + tid];
}

extern "C" void kernel_launch(void* const* d_in, const int* in_sizes, int n_in,
                              void* d_out, int out_size, void* d_ws,
                              size_t ws_size, hipStream_t stream) {
  (void)in_sizes; (void)n_in; (void)out_size; (void)d_ws; (void)ws_size;
  const float* q    = (const float*)d_in[0];
  const float* w_ih = (const float*)d_in[1];
  const float* w_hh = (const float*)d_in[2];
  const float* b_ih = (const float*)d_in[3];
  const float* b_hh = (const float*)d_in[4];
  float* out = (float*)d_out;

  proj_kernel<<<dim3((B_SZ * T_SZ / 128) * (H_SZ / 128)), dim3(256), 0,
                stream>>>(q, w_ih, b_ih, b_hh, out);

  // 131072 (W frags) + 2048 (h dbuf) = 133120 B dynamic LDS
  hipFuncSetAttribute(reinterpret_cast<const void*>(rnn_kernel),
                      hipFuncAttributeMaxDynamicSharedMemorySize, 133120);
  rnn_kernel<<<dim3(B_SZ), dim3(512), 133120, stream>>>(w_hh, out);
}

// Round 4
// 5865.385 us; speedup vs baseline: 1.1370x; 1.1370x over previous
//
#include <hip/hip_runtime.h>
#include <cstdint>

#define B_SZ 64
#define T_SZ 2048
#define F_SZ 256
#define H_SZ 512

typedef _Float16 f16x8 __attribute__((ext_vector_type(8)));
typedef float f32x4 __attribute__((ext_vector_type(4)));

#if defined(__has_builtin)
#if __has_builtin(__builtin_amdgcn_fdot2)
#define HAVE_FDOT2 1
#endif
#endif
#ifndef HAVE_FDOT2
#define HAVE_FDOT2 0
#endif

typedef _Float16 half2v __attribute__((ext_vector_type(2)));
union H2U { uint32_t u; half2v h; _Float16 e[2]; };

__device__ __forceinline__ float fdot2f(uint32_t a, uint32_t b, float c) {
  H2U ua, ub; ua.u = a; ub.u = b;
#if HAVE_FDOT2
  return __builtin_amdgcn_fdot2(ua.h, ub.h, c, false);
#else
  return c + (float)ua.e[0] * (float)ub.e[0] + (float)ua.e[1] * (float)ub.e[1];
#endif
}

__device__ __forceinline__ uint32_t pack2h(float x, float y) {
  H2U v; v.e[0] = (_Float16)x; v.e[1] = (_Float16)y; return v.u;
}

__device__ __forceinline__ float fast_tanh(float x) {
  float xc = fminf(9.0f, fmaxf(-9.0f, x));
  float e = __expf(2.0f * xc);
  return (e - 1.0f) / (e + 1.0f);
}

// ---------------------------------------------------------------------------
// Kernel 1: xp[m,n] = q·W_ih^T + b_ih + b_hh   (unchanged — ~260 us)
// ---------------------------------------------------------------------------
__global__ __launch_bounds__(256) void proj_kernel(
    const float* __restrict__ q, const float* __restrict__ w_ih,
    const float* __restrict__ b_ih, const float* __restrict__ b_hh,
    float* __restrict__ xp) {
  __shared__ uint32_t lds_a[16][128 + 4];
  __shared__ uint32_t lds_b[16][128 + 4];
  const int tid = threadIdx.x;
  const int nt = blockIdx.x & 3;
  const int mt = blockIdx.x >> 2;
  const int m0 = mt * 128, n0 = nt * 128;
  const int tx = tid & 15, ty = tid >> 4;
  const int sr = tid >> 3, sc4 = tid & 7;

  float bias[8];
#pragma unroll
  for (int j = 0; j < 8; ++j) {
    int n = n0 + tx * 8 + j;
    bias[j] = b_ih[n] + b_hh[n];
  }
  float acc[8][8];
#pragma unroll
  for (int i = 0; i < 8; ++i)
#pragma unroll
    for (int j = 0; j < 8; ++j) acc[i][j] = 0.f;

  for (int k0 = 0; k0 < F_SZ; k0 += 32) {
#pragma unroll
    for (int i = 0; i < 4; ++i) {
      int r = sr + 32 * i;
      float4 v = *(const float4*)(q + (size_t)(m0 + r) * F_SZ + k0 + sc4 * 4);
      lds_a[sc4 * 2 + 0][r] = pack2h(v.x, v.y);
      lds_a[sc4 * 2 + 1][r] = pack2h(v.z, v.w);
      float4 w = *(const float4*)(w_ih + (size_t)(n0 + r) * F_SZ + k0 + sc4 * 4);
      lds_b[sc4 * 2 + 0][r] = pack2h(w.x, w.y);
      lds_b[sc4 * 2 + 1][r] = pack2h(w.z, w.w);
    }
    __syncthreads();
#pragma unroll
    for (int kp = 0; kp < 16; ++kp) {
      uint32_t a8[8], b8[8];
#pragma unroll
      for (int i = 0; i < 8; ++i) a8[i] = lds_a[kp][ty * 8 + i];
#pragma unroll
      for (int j = 0; j < 8; ++j) b8[j] = lds_b[kp][tx * 8 + j];
#pragma unroll
      for (int i = 0; i < 8; ++i)
#pragma unroll
        for (int j = 0; j < 8; ++j)
          acc[i][j] = fdot2f(a8[i], b8[j], acc[i][j]);
    }
    __syncthreads();
  }
#pragma unroll
  for (int i = 0; i < 8; ++i) {
    size_t row = (size_t)(m0 + ty * 8 + i);
    float4 o0, o1;
    o0.x = acc[i][0] + bias[0]; o0.y = acc[i][1] + bias[1];
    o0.z = acc[i][2] + bias[2]; o0.w = acc[i][3] + bias[3];
    o1.x = acc[i][4] + bias[4]; o1.y = acc[i][5] + bias[5];
    o1.z = acc[i][6] + bias[6]; o1.w = acc[i][7] + bias[7];
    *(float4*)(xp + row * H_SZ + n0 + tx * 8) = o0;
    *(float4*)(xp + row * H_SZ + n0 + tx * 8 + 4) = o1;
  }
}

// ---------------------------------------------------------------------------
// Kernel 2: recurrence via MFMA, W_hh FULLY register-resident.
// One 512-thread WG (8 waves) per batch row; wave w owns output rows
// 64w..64w+63 as 4 row-tiles x 16 k-tiles of mfma_f32_16x16x32_f16
// A-fragments = 256 regs/thread (AGPRs; MFMA reads AGPR natively).
// LDS holds only the h double-buffer (2 x 512 f16). B-frags are 16-way
// broadcast b128 reads (conflict-free). All 16 MFMA columns compute the
// same dot; each lane statically selects one of its 16 replicated results
// (tile=m>>2, reg=m&3) -> exactly one tanh per lane, no divergence.
// C/D layout (HW-verified r3): col=lane&15, row=(lane>>4)*4+reg.
// ---------------------------------------------------------------------------
__global__ __attribute__((amdgpu_flat_work_group_size(512, 512),
                          amdgpu_waves_per_eu(2, 2)))
void rnn_kernel(const float* __restrict__ w_hh, float* __restrict__ out) {
  extern __shared__ char smem[];
  _Float16* lds_h = (_Float16*)smem;  // 2 x 512 halves (rest of LDS = pad)

  const int b = blockIdx.x;
  const int tid = threadIdx.x;
  const int w = tid >> 6;
  const int lane = tid & 63;
  const int m = lane & 15;   // A row within tile / C col
  const int g = lane >> 4;   // k-group / C row-group

  // --- A-fragments: af[tile][kt] covers row 64w+tile*16+m, k=kt*32+g*8+i ---
  f16x8 af[4][16];
#pragma unroll
  for (int tile = 0; tile < 4; ++tile) {
    const float* rowp = w_hh + (size_t)(64 * w + tile * 16 + m) * H_SZ;
#pragma unroll
    for (int kt = 0; kt < 16; ++kt) {
      const float* p = rowp + kt * 32 + g * 8;
      float4 v0 = *(const float4*)p;
      float4 v1 = *(const float4*)(p + 4);
      f16x8 a;
      a[0] = (_Float16)v0.x; a[1] = (_Float16)v0.y;
      a[2] = (_Float16)v0.z; a[3] = (_Float16)v0.w;
      a[4] = (_Float16)v1.x; a[5] = (_Float16)v1.y;
      a[6] = (_Float16)v1.z; a[7] = (_Float16)v1.w;
      af[tile][kt] = a;
    }
  }
  // h0 = 0, both buffers
  lds_h[tid] = (_Float16)0.f;
  lds_h[512 + tid] = (_Float16)0.f;
  __syncthreads();

  // this lane's output row (bijective within the block)
  const int row = 64 * w + (m >> 2) * 16 + g * 4 + (m & 3);
  const bool b8 = (m & 8) != 0, b4 = (m & 4) != 0;
  const bool b2 = (m & 2) != 0, b1 = (m & 1) != 0;

  float* outb = out + (size_t)b * T_SZ * H_SZ;
  float xc = outb[row];  // xp for t=0
  float hlast = 0.f;

#pragma unroll 1
  for (int t = 0; t < T_SZ; ++t) {
    // prefetch next xp (row t+1 not yet overwritten; at t=T-1 reads dummy)
    int tn = (t + 1 < T_SZ) ? t + 1 : t;
    float xn = outb[(size_t)tn * H_SZ + row];

    const _Float16* hb = lds_h + (t & 1) * 512;
    f32x4 c0 = {0.f, 0.f, 0.f, 0.f}, c1 = c0, c2 = c0, c3 = c0;
#pragma unroll
    for (int kt = 0; kt < 16; ++kt) {
      f16x8 bf = *(const f16x8*)(hb + kt * 32 + g * 8);  // 16-way broadcast
      c0 = __builtin_amdgcn_mfma_f32_16x16x32_f16(af[0][kt], bf, c0, 0, 0, 0);
      c1 = __builtin_amdgcn_mfma_f32_16x16x32_f16(af[1][kt], bf, c1, 0, 0, 0);
      c2 = __builtin_amdgcn_mfma_f32_16x16x32_f16(af[2][kt], bf, c2, 0, 0, 0);
      c3 = __builtin_amdgcn_mfma_f32_16x16x32_f16(af[3][kt], bf, c3, 0, 0, 0);
    }

    // static 16->1 select: tile = m>>2 (bits b8,b4), reg = m&3 (bits b2,b1)
    float p0 = b8 ? (b4 ? c3[0] : c2[0]) : (b4 ? c1[0] : c0[0]);
    float p1 = b8 ? (b4 ? c3[1] : c2[1]) : (b4 ? c1[1] : c0[1]);
    float p2 = b8 ? (b4 ? c3[2] : c2[2]) : (b4 ? c1[2] : c0[2]);
    float p3 = b8 ? (b4 ? c3[3] : c2[3]) : (b4 ? c1[3] : c0[3]);
    float q01 = b1 ? p1 : p0;
    float q23 = b1 ? p3 : p2;
    float v = b2 ? q23 : q01;

    float hnew = fast_tanh(xc + v);
    outb[(size_t)t * H_SZ + row] = hnew;                     // h_t overwrites xp
    lds_h[((t + 1) & 1) * 512 + row] = (_Float16)hnew;       // next-step h
    hlast = hnew;
    xc = xn;
    __syncthreads();
  }

  // hidden = h_{T-1}
  out[(size_t)B_SZ * T_SZ * H_SZ + (size_t)b * H_SZ + row] = hlast;
}

extern "C" void kernel_launch(void* const* d_in, const int* in_sizes, int n_in,
                              void* d_out, int out_size, void* d_ws,
                              size_t ws_size, hipStream_t stream) {
  (void)in_sizes; (void)n_in; (void)out_size; (void)d_ws; (void)ws_size;
  const float* q    = (const float*)d_in[0];
  const float* w_ih = (const float*)d_in[1];
  const float* w_hh = (const float*)d_in[2];
  const float* b_ih = (const float*)d_in[3];
  const float* b_hh = (const float*)d_in[4];
  float* out = (float*)d_out;

  proj_kernel<<<dim3((B_SZ * T_SZ / 128) * (H_SZ / 128)), dim3(256), 0,
                stream>>>(q, w_ih, b_ih, b_hh, out);

  // Only 2 KB used, but request 96 KB to pin exactly 1 WG per CU
  // (prevents 2-batch co-residency from doubling per-CU LDS traffic).
  hipFuncSetAttribute(reinterpret_cast<const void*>(rnn_kernel),
                      hipFuncAttributeMaxDynamicSharedMemorySize, 98304);
  rnn_kernel<<<dim3(B_SZ), dim3(512), 98304, stream>>>(w_hh, out);
}